// Round 20
// baseline (88.225 us; speedup 1.0000x reference)
//
#include <hip/hip_runtime.h>

#define B_SZ 256
#define N_SZ 2000
#define N_PAD 2048
#define D_SZ 512
#define C_SZ 100
#define BT 4             // batch rows per block
#define JW 4             // H8 groups (8 d's each) per block = 32 d's
#define ZSPLIT 16        // D_SZ / 32
#define NSPLIT 2         // n-sweep halves (blockIdx.z) -> 8 waves/SIMD
#define D4 (D_SZ / 4)
#define DC8 (D_SZ / 8)   // 64 H8 rows in supH

typedef __fp16 h2 __attribute__((ext_vector_type(2)));

struct alignas(16) H8 { h2 x, y, z, w; };  // 8 consecutive halves
struct alignas(8)  H4 { h2 lo, hi; };      // 4 consecutive halves

static __device__ __forceinline__ h2 habs2(h2 v) {
    unsigned u = __builtin_bit_cast(unsigned, v) & 0x7FFF7FFFu;
    return __builtin_bit_cast(h2, u);
}

#if __has_builtin(__builtin_amdgcn_fdot2)
static __device__ __forceinline__ float DOT2(h2 d, h2 wv, float c) {
    return __builtin_amdgcn_fdot2(d, wv, c, false);
}
#else
static __device__ __forceinline__ float DOT2(h2 d, h2 wv, float c) {
    return c + (float)d.x * (float)wv.x + (float)d.y * (float)wv.y;
}
#endif

// ---------------------------------------------------------------------------
// Fused setup (r17 verbatim): [0,512) transpose+convert support |
// [512,640) inputs f32->f16 | [640,648) labels->idx | [648] w->f16.
// ---------------------------------------------------------------------------
__global__ void setup_kernel(const float* __restrict__ labels,
                             const float* __restrict__ inputs,
                             const float* __restrict__ w,
                             const float4* __restrict__ sup4,
                             int* __restrict__ idx,
                             H4* __restrict__ inpH4,
                             H4* __restrict__ wH4,
                             H8* __restrict__ supH) {
    int bid = blockIdx.x, tid = threadIdx.x;
    if (bid < 512) {                     // support transpose+convert
        int t   = bid * 256 + tid;       // t = n * 64 + dc8
        int n   = t >> 6;
        int dc8 = t & 63;
        H8 o = {};
        if (n < N_SZ) {
            float4 p = sup4[(size_t)n * D4 + 2 * dc8];
            float4 q = sup4[(size_t)n * D4 + 2 * dc8 + 1];
            o.x = __builtin_amdgcn_cvt_pkrtz(p.x, p.y);
            o.y = __builtin_amdgcn_cvt_pkrtz(p.z, p.w);
            o.z = __builtin_amdgcn_cvt_pkrtz(q.x, q.y);
            o.w = __builtin_amdgcn_cvt_pkrtz(q.z, q.w);
        }
        supH[(size_t)dc8 * N_PAD + n] = o;
    } else if (bid < 640) {              // inputs convert
        int i4 = (bid - 512) * 256 + tid;    // 32768 float4
        float4 v = ((const float4*)inputs)[i4];
        H4 o;
        o.lo = __builtin_amdgcn_cvt_pkrtz(v.x, v.y);
        o.hi = __builtin_amdgcn_cvt_pkrtz(v.z, v.w);
        inpH4[i4] = o;
    } else if (bid < 648) {              // label one-hot -> class idx
        int n = (bid - 640) * 256 + tid;
        if (n < N_SZ) {
            const float4* row = (const float4*)(labels + (size_t)n * C_SZ);
            int c = 0;
#pragma unroll
            for (int j = 0; j < C_SZ / 4; ++j) {
                float4 v = row[j];
                if (v.x > 0.5f) c = 4 * j + 0;
                if (v.y > 0.5f) c = 4 * j + 1;
                if (v.z > 0.5f) c = 4 * j + 2;
                if (v.w > 0.5f) c = 4 * j + 3;
            }
            idx[n] = c;
        }
    } else {                             // w convert (128 float4)
        if (tid < D_SZ / 4) {
            float4 v = ((const float4*)w)[tid];
            H4 o;
            o.lo = __builtin_amdgcn_cvt_pkrtz(v.x, v.y);
            o.hi = __builtin_amdgcn_cvt_pkrtz(v.z, v.w);
            wH4[tid] = o;
        }
    }
}

// ---------------------------------------------------------------------------
// Main — r17 body with ONE change: n-sweep split in half via blockIdx.z
// (4 iters/block instead of 8) -> 2048 blocks -> 8 waves/SIMD (VGPR=64
// fits). Theory: score is TLP-starved latency-bound at 4 waves/SIMD;
// doubling resident waves doubles stall interleaving.
// ---------------------------------------------------------------------------
__global__ __launch_bounds__(256, 6) void score_kernel(
    const H8* __restrict__ inpH8,   // [B][DC8]
    const H8* __restrict__ supH,    // [DC8][N_PAD]
    const H8* __restrict__ wH8,     // [DC8]
    __fp16* __restrict__ S16)       // [ZSPLIT][B][N_PAD]
{
    int tid = threadIdx.x;
    int b0  = blockIdx.x * BT;
    int dc0 = blockIdx.y * JW;          // H8-row base (32 d's)
    int nh  = blockIdx.z * (N_PAD / NSPLIT);  // n-half base

    unsigned vz = 0;                // opaque zero: force vector regs
    asm volatile("" : "+v"(vz));

    H8 af[BT][JW];
    H8 wf[JW];
#pragma unroll
    for (int i = 0; i < BT; ++i) {
        const H8* ap = inpH8 + (size_t)(b0 + i) * DC8 + dc0 + vz;
#pragma unroll
        for (int j = 0; j < JW; ++j) af[i][j] = ap[j];
    }
    {
        const H8* wp = wH8 + dc0 + vz;
#pragma unroll
        for (int j = 0; j < JW; ++j) wf[j] = wp[j];
    }

    const H8* sp0 = supH + (size_t)(dc0 + 0) * N_PAD + nh + tid;
    const H8* sp1 = supH + (size_t)(dc0 + 1) * N_PAD + nh + tid;
    const H8* sp2 = supH + (size_t)(dc0 + 2) * N_PAD + nh + tid;
    const H8* sp3 = supH + (size_t)(dc0 + 3) * N_PAD + nh + tid;

    __fp16* Sp0 = S16 + ((size_t)blockIdx.y * B_SZ + b0) * N_PAD + nh + tid;

#define STEP(J, SV)                                                  \
    {                                                                \
        H8 wv = wf[J];                                               \
        _Pragma("unroll") for (int i = 0; i < BT; ++i) {             \
            H8 a = af[i][J];                                         \
            acc[i] = DOT2(habs2(a.x - SV.x), wv.x, acc[i]);          \
            acc[i] = DOT2(habs2(a.y - SV.y), wv.y, acc[i]);          \
            acc[i] = DOT2(habs2(a.z - SV.z), wv.z, acc[i]);          \
            acc[i] = DOT2(habs2(a.w - SV.w), wv.w, acc[i]);          \
        }                                                            \
    }

    H8 sv0 = sp0[0], sv1 = sp1[0], sv2 = sp2[0], sv3 = sp3[0];

#define NHALF (N_PAD / NSPLIT)
#pragma unroll 1
    for (int n0 = 0; n0 < NHALF - 256; n0 += 256) {
        float acc[BT] = {0.f, 0.f, 0.f, 0.f};
        H8 nx0 = sp0[n0 + 256];
        STEP(0, sv0);
        H8 nx1 = sp1[n0 + 256];
        STEP(1, sv1);
        H8 nx2 = sp2[n0 + 256];
        STEP(2, sv2);
        H8 nx3 = sp3[n0 + 256];
        STEP(3, sv3);
#pragma unroll
        for (int i = 0; i < BT; ++i)
            Sp0[(size_t)i * N_PAD + n0] = (__fp16)acc[i];
        sv0 = nx0; sv1 = nx1; sv2 = nx2; sv3 = nx3;
    }
    {   // epilogue n-step
        float acc[BT] = {0.f, 0.f, 0.f, 0.f};
        STEP(0, sv0); STEP(1, sv1); STEP(2, sv2); STEP(3, sv3);
#pragma unroll
        for (int i = 0; i < BT; ++i)
            Sp0[(size_t)i * N_PAD + (NHALF - 256)] = (__fp16)acc[i];
    }
#undef STEP
#undef NHALF
}

// ---------------------------------------------------------------------------
// Aggregate — r17 verbatim: one 1024-thread block per batch row. Sum 16
// f16 partials + bias -> sigmoid -> LDS class bins -> divide_no_nan.
// ---------------------------------------------------------------------------
__global__ void agg_kernel(const __fp16* __restrict__ S16,
                           const int* __restrict__ idx,
                           const float* __restrict__ bias_p,
                           float* __restrict__ out) {
    __shared__ float sums[C_SZ];
    __shared__ float cnts[C_SZ];
    int b = blockIdx.x;
    int t = threadIdx.x;
    if (t < C_SZ) { sums[t] = 0.f; cnts[t] = 0.f; }
    __syncthreads();
    float bias = *bias_p;
    for (int n = t; n < N_SZ; n += 1024) {
        float logit = bias;
#pragma unroll
        for (int z = 0; z < ZSPLIT; ++z)
            logit += (float)S16[((size_t)z * B_SZ + b) * N_PAD + n];
        float s = 1.0f / (1.0f + __expf(-logit));
        int c = idx[n];
        atomicAdd(&sums[c], s);
        atomicAdd(&cnts[c], 1.0f);
    }
    __syncthreads();
    if (t < C_SZ) {
        float cnt = cnts[t];
        out[(size_t)b * C_SZ + t] = (cnt != 0.f) ? sums[t] / cnt : 0.f;
    }
}

extern "C" void kernel_launch(void* const* d_in, const int* in_sizes, int n_in,
                              void* d_out, int out_size, void* d_ws, size_t ws_size,
                              hipStream_t stream) {
    const float* inputs  = (const float*)d_in[0]; // [B, D]
    const float* support = (const float*)d_in[1]; // [N, D]
    const float* labels  = (const float*)d_in[2]; // [N, C]
    const float* w       = (const float*)d_in[3]; // [D]
    const float* bias    = (const float*)d_in[4]; // [1]
    float* out = (float*)d_out;                   // [B, C]

    // ws layout (bytes): idx@0 (8K) | wH@8K (1K) | inpH@16K (256K) |
    // supH@512K (2M) | S16@4M (16MB f16). All written before read.
    int*     idx  = (int*)d_ws;
    H4*      wH4  = (H4*)((char*)d_ws + 8192);
    H4*      inpH = (H4*)((char*)d_ws + 16384);
    H8*      supH = (H8*)((char*)d_ws + 524288);
    __fp16*  S16  = (__fp16*)((char*)d_ws + 4 * 1024 * 1024);

    setup_kernel<<<dim3(649), dim3(256), 0, stream>>>(
        labels, inputs, w, (const float4*)support, idx, inpH, wH4, supH);

    dim3 grid(B_SZ / BT, ZSPLIT, NSPLIT); // 64 x 16 x 2 = 2048 blocks
    score_kernel<<<grid, dim3(256), 0, stream>>>(
        (const H8*)inpH, supH, (const H8*)wH4, S16);

    agg_kernel<<<dim3(B_SZ), dim3(1024), 0, stream>>>(S16, idx, bias, out);
}

// Round 21
// 37.915 us; speedup vs baseline: 2.3269x; 2.3269x over previous
//
#include <hip/hip_runtime.h>

#define B_SZ 256
#define N_SZ 2000
#define N_PAD 2048
#define D_SZ 512
#define C_SZ 100
#define BT 4             // batch rows per block
#define JW 4             // H8 groups (8 d's each) per block = 32 d's
#define ZSPLIT 16        // D_SZ / 32
#define NSPLIT 2         // n-sweep halves (blockIdx.z) -> 8 waves/SIMD
#define D4 (D_SZ / 4)
#define DC8 (D_SZ / 8)   // 64 H8 rows in supH

typedef __fp16 h2 __attribute__((ext_vector_type(2)));

struct alignas(16) H8 { h2 x, y, z, w; };  // 8 consecutive halves
struct alignas(8)  H4 { h2 lo, hi; };      // 4 consecutive halves

static __device__ __forceinline__ h2 habs2(h2 v) {
    unsigned u = __builtin_bit_cast(unsigned, v) & 0x7FFF7FFFu;
    return __builtin_bit_cast(h2, u);
}

#if __has_builtin(__builtin_amdgcn_fdot2)
static __device__ __forceinline__ float DOT2(h2 d, h2 wv, float c) {
    return __builtin_amdgcn_fdot2(d, wv, c, false);
}
#else
static __device__ __forceinline__ float DOT2(h2 d, h2 wv, float c) {
    return c + (float)d.x * (float)wv.x + (float)d.y * (float)wv.y;
}
#endif

// ---------------------------------------------------------------------------
// Fused setup (r17 verbatim): [0,512) transpose+convert support |
// [512,640) inputs f32->f16 | [640,648) labels->idx | [648] w->f16.
// ---------------------------------------------------------------------------
__global__ void setup_kernel(const float* __restrict__ labels,
                             const float* __restrict__ inputs,
                             const float* __restrict__ w,
                             const float4* __restrict__ sup4,
                             int* __restrict__ idx,
                             H4* __restrict__ inpH4,
                             H4* __restrict__ wH4,
                             H8* __restrict__ supH) {
    int bid = blockIdx.x, tid = threadIdx.x;
    if (bid < 512) {                     // support transpose+convert
        int t   = bid * 256 + tid;       // t = n * 64 + dc8
        int n   = t >> 6;
        int dc8 = t & 63;
        H8 o = {};
        if (n < N_SZ) {
            float4 p = sup4[(size_t)n * D4 + 2 * dc8];
            float4 q = sup4[(size_t)n * D4 + 2 * dc8 + 1];
            o.x = __builtin_amdgcn_cvt_pkrtz(p.x, p.y);
            o.y = __builtin_amdgcn_cvt_pkrtz(p.z, p.w);
            o.z = __builtin_amdgcn_cvt_pkrtz(q.x, q.y);
            o.w = __builtin_amdgcn_cvt_pkrtz(q.z, q.w);
        }
        supH[(size_t)dc8 * N_PAD + n] = o;
    } else if (bid < 640) {              // inputs convert
        int i4 = (bid - 512) * 256 + tid;    // 32768 float4
        float4 v = ((const float4*)inputs)[i4];
        H4 o;
        o.lo = __builtin_amdgcn_cvt_pkrtz(v.x, v.y);
        o.hi = __builtin_amdgcn_cvt_pkrtz(v.z, v.w);
        inpH4[i4] = o;
    } else if (bid < 648) {              // label one-hot -> class idx
        int n = (bid - 640) * 256 + tid;
        if (n < N_SZ) {
            const float4* row = (const float4*)(labels + (size_t)n * C_SZ);
            int c = 0;
#pragma unroll
            for (int j = 0; j < C_SZ / 4; ++j) {
                float4 v = row[j];
                if (v.x > 0.5f) c = 4 * j + 0;
                if (v.y > 0.5f) c = 4 * j + 1;
                if (v.z > 0.5f) c = 4 * j + 2;
                if (v.w > 0.5f) c = 4 * j + 3;
            }
            idx[n] = c;
        }
    } else {                             // w convert (128 float4)
        if (tid < D_SZ / 4) {
            float4 v = ((const float4*)w)[tid];
            H4 o;
            o.lo = __builtin_amdgcn_cvt_pkrtz(v.x, v.y);
            o.hi = __builtin_amdgcn_cvt_pkrtz(v.z, v.w);
            wH4[tid] = o;
        }
    }
}

// ---------------------------------------------------------------------------
// Main — r20 structure with the corrected occupancy knob. r20's failure:
// launch_bounds(256,6) capped VGPR at 40 < the ~80-reg af/wf set -> scratch
// spill (FETCH 6MB->145MB, score 75us). Fix: launch_bounds(256,4) (cap 128;
// compiler picks ~64, no spill). VGPR=64 => 8 waves/SIMD *possible*; the
// NSPLIT=2 grid (2048 blocks = 8 blocks/CU) *delivers* them.
// ---------------------------------------------------------------------------
__global__ __launch_bounds__(256, 4) void score_kernel(
    const H8* __restrict__ inpH8,   // [B][DC8]
    const H8* __restrict__ supH,    // [DC8][N_PAD]
    const H8* __restrict__ wH8,     // [DC8]
    __fp16* __restrict__ S16)       // [ZSPLIT][B][N_PAD]
{
    int tid = threadIdx.x;
    int b0  = blockIdx.x * BT;
    int dc0 = blockIdx.y * JW;          // H8-row base (32 d's)
    int nh  = blockIdx.z * (N_PAD / NSPLIT);  // n-half base

    unsigned vz = 0;                // opaque zero: force vector regs
    asm volatile("" : "+v"(vz));

    H8 af[BT][JW];
    H8 wf[JW];
#pragma unroll
    for (int i = 0; i < BT; ++i) {
        const H8* ap = inpH8 + (size_t)(b0 + i) * DC8 + dc0 + vz;
#pragma unroll
        for (int j = 0; j < JW; ++j) af[i][j] = ap[j];
    }
    {
        const H8* wp = wH8 + dc0 + vz;
#pragma unroll
        for (int j = 0; j < JW; ++j) wf[j] = wp[j];
    }

    const H8* sp0 = supH + (size_t)(dc0 + 0) * N_PAD + nh + tid;
    const H8* sp1 = supH + (size_t)(dc0 + 1) * N_PAD + nh + tid;
    const H8* sp2 = supH + (size_t)(dc0 + 2) * N_PAD + nh + tid;
    const H8* sp3 = supH + (size_t)(dc0 + 3) * N_PAD + nh + tid;

    __fp16* Sp0 = S16 + ((size_t)blockIdx.y * B_SZ + b0) * N_PAD + nh + tid;

#define STEP(J, SV)                                                  \
    {                                                                \
        H8 wv = wf[J];                                               \
        _Pragma("unroll") for (int i = 0; i < BT; ++i) {             \
            H8 a = af[i][J];                                         \
            acc[i] = DOT2(habs2(a.x - SV.x), wv.x, acc[i]);          \
            acc[i] = DOT2(habs2(a.y - SV.y), wv.y, acc[i]);          \
            acc[i] = DOT2(habs2(a.z - SV.z), wv.z, acc[i]);          \
            acc[i] = DOT2(habs2(a.w - SV.w), wv.w, acc[i]);          \
        }                                                            \
    }

    H8 sv0 = sp0[0], sv1 = sp1[0], sv2 = sp2[0], sv3 = sp3[0];

#define NHALF (N_PAD / NSPLIT)
#pragma unroll 1
    for (int n0 = 0; n0 < NHALF - 256; n0 += 256) {
        float acc[BT] = {0.f, 0.f, 0.f, 0.f};
        H8 nx0 = sp0[n0 + 256];
        STEP(0, sv0);
        H8 nx1 = sp1[n0 + 256];
        STEP(1, sv1);
        H8 nx2 = sp2[n0 + 256];
        STEP(2, sv2);
        H8 nx3 = sp3[n0 + 256];
        STEP(3, sv3);
#pragma unroll
        for (int i = 0; i < BT; ++i)
            Sp0[(size_t)i * N_PAD + n0] = (__fp16)acc[i];
        sv0 = nx0; sv1 = nx1; sv2 = nx2; sv3 = nx3;
    }
    {   // epilogue n-step
        float acc[BT] = {0.f, 0.f, 0.f, 0.f};
        STEP(0, sv0); STEP(1, sv1); STEP(2, sv2); STEP(3, sv3);
#pragma unroll
        for (int i = 0; i < BT; ++i)
            Sp0[(size_t)i * N_PAD + (NHALF - 256)] = (__fp16)acc[i];
    }
#undef STEP
#undef NHALF
}

// ---------------------------------------------------------------------------
// Aggregate — r17 verbatim: one 1024-thread block per batch row. Sum 16
// f16 partials + bias -> sigmoid -> LDS class bins -> divide_no_nan.
// ---------------------------------------------------------------------------
__global__ void agg_kernel(const __fp16* __restrict__ S16,
                           const int* __restrict__ idx,
                           const float* __restrict__ bias_p,
                           float* __restrict__ out) {
    __shared__ float sums[C_SZ];
    __shared__ float cnts[C_SZ];
    int b = blockIdx.x;
    int t = threadIdx.x;
    if (t < C_SZ) { sums[t] = 0.f; cnts[t] = 0.f; }
    __syncthreads();
    float bias = *bias_p;
    for (int n = t; n < N_SZ; n += 1024) {
        float logit = bias;
#pragma unroll
        for (int z = 0; z < ZSPLIT; ++z)
            logit += (float)S16[((size_t)z * B_SZ + b) * N_PAD + n];
        float s = 1.0f / (1.0f + __expf(-logit));
        int c = idx[n];
        atomicAdd(&sums[c], s);
        atomicAdd(&cnts[c], 1.0f);
    }
    __syncthreads();
    if (t < C_SZ) {
        float cnt = cnts[t];
        out[(size_t)b * C_SZ + t] = (cnt != 0.f) ? sums[t] / cnt : 0.f;
    }
}

extern "C" void kernel_launch(void* const* d_in, const int* in_sizes, int n_in,
                              void* d_out, int out_size, void* d_ws, size_t ws_size,
                              hipStream_t stream) {
    const float* inputs  = (const float*)d_in[0]; // [B, D]
    const float* support = (const float*)d_in[1]; // [N, D]
    const float* labels  = (const float*)d_in[2]; // [N, C]
    const float* w       = (const float*)d_in[3]; // [D]
    const float* bias    = (const float*)d_in[4]; // [1]
    float* out = (float*)d_out;                   // [B, C]

    // ws layout (bytes): idx@0 (8K) | wH@8K (1K) | inpH@16K (256K) |
    // supH@512K (2M) | S16@4M (16MB f16). All written before read.
    int*     idx  = (int*)d_ws;
    H4*      wH4  = (H4*)((char*)d_ws + 8192);
    H4*      inpH = (H4*)((char*)d_ws + 16384);
    H8*      supH = (H8*)((char*)d_ws + 524288);
    __fp16*  S16  = (__fp16*)((char*)d_ws + 4 * 1024 * 1024);

    setup_kernel<<<dim3(649), dim3(256), 0, stream>>>(
        labels, inputs, w, (const float4*)support, idx, inpH, wH4, supH);

    dim3 grid(B_SZ / BT, ZSPLIT, NSPLIT); // 64 x 16 x 2 = 2048 blocks
    score_kernel<<<grid, dim3(256), 0, stream>>>(
        (const H8*)inpH, supH, (const H8*)wH4, S16);

    agg_kernel<<<dim3(B_SZ), dim3(1024), 0, stream>>>(S16, idx, bias, out);
}